// Round 1
// baseline (18845.872 us; speedup 1.0000x reference)
//
#include <hip/hip_runtime.h>
#include <cstddef>

#define HID 1024
#define H3 3072
#define BATCH 128
#define TT 256
#define N_INH 717   // HID - int(0.3*HID) = 1024 - 307

__device__ __forceinline__ float clipf(float w) {
    return fminf(fmaxf(w, 1e-10f), 1.0f);
}

// ---------------------------------------------------------------------------
// Build W_rec [3072][3072] fp32 row-major into workspace.
// Row blocks: 0=str, 1=thal, 2=m1. Col blocks: 0=str, 1=thal, 2=m1.
// ---------------------------------------------------------------------------
__global__ __launch_bounds__(256) void build_w(
    const float* __restrict__ s2s_fixed,
    const float* __restrict__ s2t_w,
    const float* __restrict__ m2s_w,
    const float* __restrict__ t2m_w,
    const float* __restrict__ m2m_w,
    float* __restrict__ W)
{
    int j = blockIdx.x * 256 + threadIdx.x;   // col 0..3071
    int i = blockIdx.y;                       // row 0..3071
    int rb = i >> 10, ri = i & 1023;
    int cb = j >> 10, cj = j & 1023;
    float v = 0.0f;
    if (rb == 0) {
        if (cb == 0) {
            // str2str_rec = (0*clip + fixed) * (-1)
            v = -s2s_fixed[ri * HID + cj];
        } else if (cb == 2) {
            v = (cj < N_INH) ? clipf(m2s_w[ri * HID + cj]) : 0.0f;
        }
    } else if (rb == 1) {
        if (cb == 0) {
            v = clipf(s2t_w[ri * HID + cj]) * (cj < (HID / 2) ? 1.0f : -1.0f);
        }
    } else {
        if (cb == 1) {
            v = clipf(t2m_w[ri * HID + cj]);
        } else if (cb == 2) {
            v = clipf(m2m_w[ri * HID + cj]) * (cj < N_INH ? 1.0f : -1.0f);
        }
    }
    W[(size_t)i * H3 + j] = v;
}

// ---------------------------------------------------------------------------
// One recurrence step: out[b,i] = relu(0.9*x0[b,i] + 0.1*(sum_j W[i,j]*h[b,j] + p))
// p = sum_c inp[b,t,c] * iw[c,i]
// Tiles: BM=32 (batch) x BN=64 (units), 256 threads, 8 outputs/thread (2x4).
// K restricted to the nonzero 1024-blocks of W for this output row-block.
// ---------------------------------------------------------------------------
__global__ __launch_bounds__(256) void step_kernel(
    const float* __restrict__ W,       // [3072][3072]
    const float* __restrict__ h_prev,  // h[b,j] at h_prev[b*h_bstride + j]
    const long long h_bstride,
    const float* __restrict__ x0,      // [B][3072]
    const float* __restrict__ inp,     // [B][T][4]
    const float* __restrict__ iw,      // [4][3072]
    float* __restrict__ rnn_out,       // [B][T][3072]
    const int t)
{
    __shared__ float hs[32][34];    // [k][m], pad for b64-aligned float2 reads
    __shared__ float wsm[32][68];   // [k][n], pad for b128-aligned float4 reads

    const int tx = threadIdx.x;
    const int n0 = blockIdx.x * 64;   // unit tile base
    const int b0 = blockIdx.y * 32;   // batch tile base
    const int ib = n0 >> 10;          // output row-block of W (0=str,1=thal,2=m1)

    int kb[2];
    int nk;
    if (ib == 0)      { kb[0] = 0;    kb[1] = 2048; nk = 2; }
    else if (ib == 1) { kb[0] = 0;    kb[1] = 0;    nk = 1; }
    else              { kb[0] = 1024; kb[1] = 2048; nk = 2; }

    const int tm = tx & 15;   // rows 2*tm, 2*tm+1
    const int tn = tx >> 4;   // cols 4*tn .. 4*tn+3

    float acc[2][4] = {{0.f, 0.f, 0.f, 0.f}, {0.f, 0.f, 0.f, 0.f}};

    for (int kki = 0; kki < nk; ++kki) {
        const int kbase = kb[kki];
        for (int k0 = 0; k0 < 1024; k0 += 32) {
            const int kk = kbase + k0;
            // stage h tile [32 b x 32 k] -> hs[k][m]
            {
                int idx = tx;
#pragma unroll
                for (int e = 0; e < 4; ++e) {
                    int m = idx >> 5, k = idx & 31;
                    hs[k][m] = h_prev[(size_t)(b0 + m) * h_bstride + kk + k];
                    idx += 256;
                }
            }
            // stage W tile [64 n x 32 k] -> wsm[k][n]
            {
                int idx = tx;
#pragma unroll
                for (int e = 0; e < 8; ++e) {
                    int n = idx >> 5, k = idx & 31;
                    wsm[k][n] = W[(size_t)(n0 + n) * H3 + kk + k];
                    idx += 256;
                }
            }
            __syncthreads();
#pragma unroll
            for (int k = 0; k < 32; ++k) {
                float2 a = *(const float2*)&hs[k][2 * tm];
                float4 bv = *(const float4*)&wsm[k][4 * tn];
                acc[0][0] += a.x * bv.x; acc[0][1] += a.x * bv.y;
                acc[0][2] += a.x * bv.z; acc[0][3] += a.x * bv.w;
                acc[1][0] += a.y * bv.x; acc[1][1] += a.y * bv.y;
                acc[1][2] += a.y * bv.z; acc[1][3] += a.y * bv.w;
            }
            __syncthreads();
        }
    }

    // epilogue: input projection + leak + relu + store
#pragma unroll
    for (int r = 0; r < 2; ++r) {
        const int b = b0 + 2 * tm + r;
        const float i0 = inp[b * (TT * 4) + t * 4 + 0];
        const float i1 = inp[b * (TT * 4) + t * 4 + 1];
        const float i2 = inp[b * (TT * 4) + t * 4 + 2];
        const float i3 = inp[b * (TT * 4) + t * 4 + 3];
#pragma unroll
        for (int c = 0; c < 4; ++c) {
            const int n = n0 + 4 * tn + c;
            float pv = i0 * iw[n] + i1 * iw[H3 + n] + i2 * iw[2 * H3 + n]
                     + i3 * iw[3 * H3 + n];
            float v = 0.9f * x0[b * H3 + n] + 0.1f * (acc[r][c] + pv);
            rnn_out[(size_t)b * TT * H3 + (size_t)t * H3 + n] = fmaxf(v, 0.0f);
        }
    }
}

// ---------------------------------------------------------------------------
// x_out[b,t,:] = x0[b,:]  (B*T*3H elements, float4 grid-stride-free direct map)
// ---------------------------------------------------------------------------
__global__ __launch_bounds__(256) void xout_kernel(
    const float* __restrict__ x0, float* __restrict__ x_out)
{
    size_t idx = ((size_t)blockIdx.x * 256 + threadIdx.x) * 4;
    size_t bt = idx / H3;
    int i = (int)(idx - bt * H3);
    int b = (int)(bt >> 8);
    float4 v = *(const float4*)(x0 + (size_t)b * H3 + i);
    *(float4*)(x_out + idx) = v;
}

// ---------------------------------------------------------------------------
// hn_last = rnn_out[:, T-1, :];  x_last = x0   (each [B][3072])
// ---------------------------------------------------------------------------
__global__ __launch_bounds__(256) void last_kernel(
    const float* __restrict__ rnn_out, const float* __restrict__ x0,
    float* __restrict__ hn_last, float* __restrict__ x_last)
{
    int idx = (blockIdx.x * 256 + threadIdx.x) * 4;   // 0..393215
    int b = idx / H3;
    int i = idx - b * H3;
    *(float4*)(hn_last + idx) =
        *(const float4*)(rnn_out + (size_t)b * TT * H3 + (size_t)(TT - 1) * H3 + i);
    *(float4*)(x_last + idx) = *(const float4*)(x0 + idx);
}

// ---------------------------------------------------------------------------
// mean_out/std_out: per (b,t) dot over last 1024 channels (alm_mask).
// One wave per (b,t); 4 waves per block.
// ---------------------------------------------------------------------------
__global__ __launch_bounds__(256) void tail_kernel(
    const float* __restrict__ rnn_out,
    const float* __restrict__ mW, const float* __restrict__ mb,
    const float* __restrict__ sW, const float* __restrict__ sb,
    float* __restrict__ mean_out, float* __restrict__ std_out)
{
    int wid = blockIdx.x * 4 + (threadIdx.x >> 6);   // b*T + t
    int lane = threadIdx.x & 63;
    int b = wid >> 8, t = wid & 255;
    const float* row = rnn_out + (size_t)b * TT * H3 + (size_t)t * H3 + 2048;
    const int j0 = lane * 16;
    float sm = 0.f, ss = 0.f;
#pragma unroll
    for (int e = 0; e < 16; e += 4) {
        float4 v  = *(const float4*)(row + j0 + e);
        float4 wm = *(const float4*)(mW + 2048 + j0 + e);
        float4 wv = *(const float4*)(sW + 2048 + j0 + e);
        sm += v.x * wm.x + v.y * wm.y + v.z * wm.z + v.w * wm.w;
        ss += v.x * wv.x + v.y * wv.y + v.z * wv.z + v.w * wv.w;
    }
#pragma unroll
    for (int off = 32; off; off >>= 1) {
        sm += __shfl_down(sm, off);
        ss += __shfl_down(ss, off);
    }
    if (lane == 0) {
        mean_out[wid] = sm + mb[0];
        std_out[wid]  = ss + sb[0];
    }
}

// ---------------------------------------------------------------------------
extern "C" void kernel_launch(void* const* d_in, const int* in_sizes, int n_in,
                              void* d_out, int out_size, void* d_ws, size_t ws_size,
                              hipStream_t stream)
{
    const float* inp        = (const float*)d_in[0];
    const float* hn         = (const float*)d_in[1];
    const float* x          = (const float*)d_in[2];
    // d_in[3] = str2str_w (unused: str2str_mask is all-zero in the reference)
    const float* str2thal_w = (const float*)d_in[4];
    const float* m12m1_w    = (const float*)d_in[5];
    const float* m12str_w   = (const float*)d_in[6];
    const float* thal2m1_w  = (const float*)d_in[7];
    const float* s2s_fixed  = (const float*)d_in[8];
    const float* iw         = (const float*)d_in[9];
    const float* mean_W     = (const float*)d_in[10];
    const float* mean_b     = (const float*)d_in[11];
    const float* std_W      = (const float*)d_in[12];
    const float* std_b      = (const float*)d_in[13];

    float* out      = (float*)d_out;
    float* mean_out = out;                              // [B,T,1]   32768
    float* std_out  = out + 32768;                      // [B,T,1]   32768
    float* rnn_out  = out + 65536;                      // [B,T,3H]  100663296
    float* hn_last  = out + 100728832;                  // [1,B,3H]  393216
    float* x_last   = out + 101122048;                  // [1,B,3H]  393216
    float* x_out    = out + 101515264;                  // [B,T,3H]  100663296

    float* W = (float*)d_ws;                            // 3072*3072*4 = 37.75 MB

    build_w<<<dim3(12, H3), 256, 0, stream>>>(s2s_fixed, str2thal_w, m12str_w,
                                              thal2m1_w, m12m1_w, W);
    xout_kernel<<<98304, 256, 0, stream>>>(x, x_out);

    for (int t = 0; t < TT; ++t) {
        const float* h_prev = (t == 0) ? hn : (rnn_out + (size_t)(t - 1) * H3);
        const long long hb  = (t == 0) ? (long long)H3 : (long long)TT * H3;
        step_kernel<<<dim3(48, 4), 256, 0, stream>>>(W, h_prev, hb, x, inp, iw,
                                                     rnn_out, t);
    }

    last_kernel<<<384, 256, 0, stream>>>(rnn_out, x, hn_last, x_last);
    tail_kernel<<<8192, 256, 0, stream>>>(rnn_out, mean_W, mean_b,
                                          std_W, std_b, mean_out, std_out);
}